// Round 2
// baseline (509.983 us; speedup 1.0000x reference)
//
#include <hip/hip_runtime.h>

// Problem constants (fixed by setup_inputs)
constexpr int NB = 4;
constexpr int NI = 512;
constexpr int NK = 512;
constexpr int NC = 64;
constexpr float LN_EPS = 1e-5f;

// ---------------------------------------------------------------------------
// k_S: S[b,k,c] = sum_i exp(z[b,i,k,c]) * (z_mask[b,i,k] + 1e-6)
// grid = NB * 32 k-tiles * 16 i-chunks = 2048 blocks, 256 thr
// 2-way i-unroll with independent accumulators for MLP.
// ---------------------------------------------------------------------------
__global__ __launch_bounds__(256) void k_S(const float* __restrict__ z,
                                           const float* __restrict__ zmask,
                                           float* __restrict__ S) {
    int idx = blockIdx.x;
    int ic = idx & 15; idx >>= 4;   // i-chunk 0..15 (32 i's each)
    int kt = idx & 31; int b = idx >> 5;
    int tid = threadIdx.x;
    int kk = tid >> 4;              // 0..15
    int c4 = tid & 15;              // 0..15
    int k = kt * 16 + kk;

    float4 a0 = make_float4(0.f, 0.f, 0.f, 0.f);
    float4 a1 = make_float4(0.f, 0.f, 0.f, 0.f);
    for (int ii = 0; ii < 16; ++ii) {
        int i0 = ic * 32 + ii;
        int i1 = i0 + 16;
        size_t r0 = ((size_t)(b * NI + i0) * NK + k) * NC;
        size_t r1 = ((size_t)(b * NI + i1) * NK + k) * NC;
        const float4 z0 = *(const float4*)(z + r0 + c4 * 4);
        const float4 z1 = *(const float4*)(z + r1 + c4 * 4);
        float m0 = zmask[(size_t)(b * NI + i0) * NK + k] + 1e-6f;
        float m1 = zmask[(size_t)(b * NI + i1) * NK + k] + 1e-6f;
        a0.x += __expf(z0.x) * m0;
        a0.y += __expf(z0.y) * m0;
        a0.z += __expf(z0.z) * m0;
        a0.w += __expf(z0.w) * m0;
        a1.x += __expf(z1.x) * m1;
        a1.y += __expf(z1.y) * m1;
        a1.z += __expf(z1.z) * m1;
        a1.w += __expf(z1.w) * m1;
    }
    a0.x += a1.x; a0.y += a1.y; a0.z += a1.z; a0.w += a1.w;
    float* sp = S + (size_t)(b * NK + k) * NC + c4 * 4;
    atomicAdd(sp + 0, a0.x);
    atomicAdd(sp + 1, a0.y);
    atomicAdd(sp + 2, a0.z);
    atomicAdd(sp + 3, a0.w);
}

// ---------------------------------------------------------------------------
// k_R: R[b,k,c] = (dot(Q[b,k,:], W1[c,:]) + b1[c]) / S[b,k,c]
// grid = NB*NK blocks of 64 threads (one per c)
// ---------------------------------------------------------------------------
__global__ __launch_bounds__(64) void k_R(const float* __restrict__ Q,
                                          const float* __restrict__ W1,
                                          const float* __restrict__ b1,
                                          const float* __restrict__ S,
                                          float* __restrict__ R) {
    int bk = blockIdx.x;
    int c = threadIdx.x;
    __shared__ float q[NC];
    q[c] = Q[(size_t)bk * NC + c];
    __syncthreads();
    const float* w = W1 + c * NC;
    float acc = b1[c];
#pragma unroll
    for (int j = 0; j < NC; ++j) acc += q[j] * w[j];
    R[(size_t)bk * NC + c] = acc / S[(size_t)bk * NC + c];
}

// ---------------------------------------------------------------------------
// k_Va: Va[b,i,c] = sum_k mask*(mask+1e-6)*exp(z[b,i,k,c]) * R[b,k,c]
// grid = NB*NI blocks, 256 thr (16 k-stripes x 16 float4-of-c), 2-way k-unroll.
// Atomically accumulates per-batch LN1 (sum, sumsq) into stats1.
// ---------------------------------------------------------------------------
__global__ __launch_bounds__(256) void k_Va(const float* __restrict__ z,
                                            const float* __restrict__ zmask,
                                            const float* __restrict__ R,
                                            float* __restrict__ Va,
                                            float* __restrict__ stats1) {
    int bi = blockIdx.x;
    int b = bi >> 9;                 // / NI
    int tid = threadIdx.x;
    int kk = tid >> 4;
    int c4 = tid & 15;

    const float* zrow = z + (size_t)bi * NK * NC;
    const float* mrow = zmask + (size_t)bi * NK;
    const float* Rb = R + (size_t)b * NK * NC;

    float4 a0 = make_float4(0.f, 0.f, 0.f, 0.f);
    float4 a1 = make_float4(0.f, 0.f, 0.f, 0.f);
    for (int kb = 0; kb < 16; ++kb) {
        int k0 = kb * 16 + kk;
        int k1 = k0 + 256;
        const float4 z0 = *(const float4*)(zrow + (size_t)k0 * NC + c4 * 4);
        const float4 z1 = *(const float4*)(zrow + (size_t)k1 * NC + c4 * 4);
        const float4 r0 = *(const float4*)(Rb + (size_t)k0 * NC + c4 * 4);
        const float4 r1 = *(const float4*)(Rb + (size_t)k1 * NC + c4 * 4);
        float m0 = mrow[k0], mm0 = m0 * (m0 + 1e-6f);
        float m1 = mrow[k1], mm1 = m1 * (m1 + 1e-6f);
        a0.x += __expf(z0.x) * mm0 * r0.x;
        a0.y += __expf(z0.y) * mm0 * r0.y;
        a0.z += __expf(z0.z) * mm0 * r0.z;
        a0.w += __expf(z0.w) * mm0 * r0.w;
        a1.x += __expf(z1.x) * mm1 * r1.x;
        a1.y += __expf(z1.y) * mm1 * r1.y;
        a1.z += __expf(z1.z) * mm1 * r1.z;
        a1.w += __expf(z1.w) * mm1 * r1.w;
    }
    a0.x += a1.x; a0.y += a1.y; a0.z += a1.z; a0.w += a1.w;

    __shared__ float4 part[256];
    part[tid] = a0;
    __syncthreads();
    if (tid < 16) {
        float4 v = part[tid];
#pragma unroll
        for (int s = 1; s < 16; ++s) {
            float4 o = part[s * 16 + tid];
            v.x += o.x; v.y += o.y; v.z += o.z; v.w += o.w;
        }
        *(float4*)(Va + (size_t)bi * NC + tid * 4) = v;
        float s0 = v.x + v.y + v.z + v.w;
        float s1 = v.x * v.x + v.y * v.y + v.z * v.z + v.w * v.w;
        // reduce across the 16 active lanes (lane0's tree touches only lanes 0..15)
        s0 += __shfl_down(s0, 8); s1 += __shfl_down(s1, 8);
        s0 += __shfl_down(s0, 4); s1 += __shfl_down(s1, 4);
        s0 += __shfl_down(s0, 2); s1 += __shfl_down(s1, 2);
        s0 += __shfl_down(s0, 1); s1 += __shfl_down(s1, 1);
        if (tid == 0) {
            atomicAdd(&stats1[b * 2],     s0);
            atomicAdd(&stats1[b * 2 + 1], s1);
        }
    }
}

// ---------------------------------------------------------------------------
// k_Y: Y[b,i,c] = V + (LN1(Va) @ W2^T + b2); atomically accumulates LN2 stats.
// grid = NB*NI, block = 64 (one wave)
// ---------------------------------------------------------------------------
__global__ __launch_bounds__(64) void k_Y(const float* __restrict__ V,
                                          const float* __restrict__ W2,
                                          const float* __restrict__ b2,
                                          const float* __restrict__ Va,
                                          const float* __restrict__ stats1,
                                          float* __restrict__ Y,
                                          float* __restrict__ stats2) {
    int bi = blockIdx.x;
    int b = bi >> 9;
    int c = threadIdx.x;
    const float n = (float)(NI * NC);
    float mu = stats1[b * 2] / n;
    float var = stats1[b * 2 + 1] / n - mu * mu;
    float rstd = rsqrtf(var + LN_EPS);

    __shared__ float xn[NC];
    xn[c] = (Va[(size_t)bi * NC + c] - mu) * rstd;
    __syncthreads();

    const float* w = W2 + c * NC;
    float acc = b2[c];
#pragma unroll
    for (int j = 0; j < NC; ++j) acc += xn[j] * w[j];
    float y = V[(size_t)bi * NC + c] + acc;
    Y[(size_t)bi * NC + c] = y;

    float s0 = y, s1 = y * y;
    for (int off = 32; off; off >>= 1) {
        s0 += __shfl_down(s0, off);
        s1 += __shfl_down(s1, off);
    }
    if (c == 0) {
        atomicAdd(&stats2[b * 2],     s0);
        atomicAdd(&stats2[b * 2 + 1], s1);
    }
}

// ---------------------------------------------------------------------------
// k_out: out = LN2(Y), elementwise with per-b stats
// ---------------------------------------------------------------------------
__global__ __launch_bounds__(256) void k_out(const float* __restrict__ Y,
                                             const float* __restrict__ stats2,
                                             float* __restrict__ out) {
    int idx = blockIdx.x * 256 + threadIdx.x;
    int b = idx >> 15;               // / (NI*NC)
    const float n = (float)(NI * NC);
    float mu = stats2[b * 2] / n;
    float var = stats2[b * 2 + 1] / n - mu * mu;
    float rstd = rsqrtf(var + LN_EPS);
    out[idx] = (Y[idx] - mu) * rstd;
}

// ---------------------------------------------------------------------------
extern "C" void kernel_launch(void* const* d_in, const int* in_sizes, int n_in,
                              void* d_out, int out_size, void* d_ws, size_t ws_size,
                              hipStream_t stream) {
    const float* V  = (const float*)d_in[0];
    const float* Q  = (const float*)d_in[1];
    const float* z  = (const float*)d_in[2];
    const float* zm = (const float*)d_in[3];
    const float* W1 = (const float*)d_in[4];
    const float* b1 = (const float*)d_in[5];
    const float* W2 = (const float*)d_in[6];
    const float* b2 = (const float*)d_in[7];
    // d_in[8] is dim == 1 (fixed by setup_inputs)

    float* ws     = (float*)d_ws;
    float* S      = ws;                         // 131072 floats
    float* stats1 = ws + 131072;                // 8
    float* stats2 = ws + 131080;                // 8
    float* R      = ws + 131088;                // 131072 (16B-aligned)
    float* Va     = ws + 262160;                // 131072
    float* Y      = ws + 393232;                // 131072

    // zero S + stats1 + stats2 in one memset
    hipMemsetAsync(S, 0, (131072 + 16) * sizeof(float), stream);

    k_S  <<<NB * 32 * 16, 256, 0, stream>>>(z, zm, S);
    k_R  <<<NB * NK,      64,  0, stream>>>(Q, W1, b1, S, R);
    k_Va <<<NB * NI,      256, 0, stream>>>(z, zm, R, Va, stats1);
    k_Y  <<<NB * NI,      64,  0, stream>>>(V, W2, b2, Va, stats1, Y, stats2);
    k_out<<<(NB * NI * NC) / 256, 256, 0, stream>>>(Y, stats2, (float*)d_out);
}

// Round 3
// 464.266 us; speedup vs baseline: 1.0985x; 1.0985x over previous
//
#include <hip/hip_runtime.h>

// Problem constants (fixed by setup_inputs)
constexpr int NB = 4;
constexpr int NI = 512;
constexpr int NK = 512;
constexpr int NC = 64;
constexpr float LN_EPS = 1e-5f;

// ---------------------------------------------------------------------------
// k_S: S[b,k,c] += sum_i exp(z[b,i,k,c]) * (z_mask[b,i,k] + 1e-6)   (batch b)
// grid = 512 blocks (32 k-tiles x 16 i-chunks), block = 256 (16 k x 16 c4)
// ---------------------------------------------------------------------------
__global__ __launch_bounds__(256) void k_S(const float* __restrict__ z,
                                           const float* __restrict__ zmask,
                                           float* __restrict__ S, int b) {
    int idx = blockIdx.x;
    int ic = idx & 15;              // i-chunk 0..15 (32 i's each)
    int kt = idx >> 4;              // k-tile 0..31
    int tid = threadIdx.x;
    int kk = tid >> 4;              // 0..15
    int c4 = tid & 15;              // 0..15
    int k = kt * 16 + kk;

    float4 acc = make_float4(0.f, 0.f, 0.f, 0.f);
    for (int ii = 0; ii < 32; ++ii) {
        int i = ic * 32 + ii;
        size_t row = ((size_t)(b * NI + i) * NK + k) * NC;
        const float4 zv = *(const float4*)(z + row + c4 * 4);
        float m = zmask[(size_t)(b * NI + i) * NK + k] + 1e-6f;
        acc.x += __expf(zv.x) * m;
        acc.y += __expf(zv.y) * m;
        acc.z += __expf(zv.z) * m;
        acc.w += __expf(zv.w) * m;
    }
    float* sp = S + (size_t)(b * NK + k) * NC + c4 * 4;
    atomicAdd(sp + 0, acc.x);
    atomicAdd(sp + 1, acc.y);
    atomicAdd(sp + 2, acc.z);
    atomicAdd(sp + 3, acc.w);
}

// ---------------------------------------------------------------------------
// k_R: R[b,k,c] = (dot(Q[b,k,:], W1[c,:]) + b1[c]) / S[b,k,c]   (batch b)
// grid = 512 blocks of 64 threads (one per c)
// ---------------------------------------------------------------------------
__global__ __launch_bounds__(64) void k_R(const float* __restrict__ Q,
                                          const float* __restrict__ W1,
                                          const float* __restrict__ b1,
                                          const float* __restrict__ S,
                                          float* __restrict__ R, int b) {
    int bk = b * NK + blockIdx.x;
    int c = threadIdx.x;
    __shared__ float q[NC];
    q[c] = Q[(size_t)bk * NC + c];
    __syncthreads();
    const float* w = W1 + c * NC;
    float acc = b1[c];
#pragma unroll
    for (int j = 0; j < NC; ++j) acc += q[j] * w[j];
    R[(size_t)bk * NC + c] = acc / S[(size_t)bk * NC + c];
}

// ---------------------------------------------------------------------------
// k_Va: Va[b,i,c] = sum_k mask*(mask+1e-6)*exp(z[b,i,k,c]) * R[b,k,c]  (batch b)
// grid = 512 blocks (one per i), block = 256 (16 k-stripes x 16 float4-of-c)
// Emits per-(b,i) partial (sum, sumsq) for LN1.
// ---------------------------------------------------------------------------
__global__ __launch_bounds__(256) void k_Va(const float* __restrict__ z,
                                            const float* __restrict__ zmask,
                                            const float* __restrict__ R,
                                            float* __restrict__ Va,
                                            float* __restrict__ part1, int b) {
    int bi = b * NI + blockIdx.x;
    int tid = threadIdx.x;
    int kk = tid >> 4;
    int c4 = tid & 15;

    const float* zrow = z + (size_t)bi * NK * NC;
    const float* mrow = zmask + (size_t)bi * NK;
    const float* Rb = R + (size_t)b * NK * NC;

    float4 acc = make_float4(0.f, 0.f, 0.f, 0.f);
    for (int kb = 0; kb < NK / 16; ++kb) {
        int k = kb * 16 + kk;
        const float4 zv = *(const float4*)(zrow + (size_t)k * NC + c4 * 4);
        const float4 rv = *(const float4*)(Rb + (size_t)k * NC + c4 * 4);
        float zm = mrow[k];
        float m2 = zm * (zm + 1e-6f);
        acc.x += __expf(zv.x) * m2 * rv.x;
        acc.y += __expf(zv.y) * m2 * rv.y;
        acc.z += __expf(zv.z) * m2 * rv.z;
        acc.w += __expf(zv.w) * m2 * rv.w;
    }

    __shared__ float4 part[256];
    part[tid] = acc;
    __syncthreads();
    // reduce across the 16 kk-stripes (tid = kk*16 + c4)
    for (int s = 128; s >= 16; s >>= 1) {
        if (tid < s) {
            float4 o = part[tid + s];
            float4 m = part[tid];
            m.x += o.x; m.y += o.y; m.z += o.z; m.w += o.w;
            part[tid] = m;
        }
        __syncthreads();
    }
    __shared__ float red[32];
    if (tid < 16) {
        float4 v = part[tid];
        *(float4*)(Va + (size_t)bi * NC + tid * 4) = v;
        red[tid]      = v.x + v.y + v.z + v.w;
        red[16 + tid] = v.x * v.x + v.y * v.y + v.z * v.z + v.w * v.w;
    }
    __syncthreads();
    if (tid == 0) {
        float s0 = 0.f, s1 = 0.f;
        for (int t = 0; t < 16; ++t) { s0 += red[t]; s1 += red[16 + t]; }
        part1[bi * 2]     = s0;
        part1[bi * 2 + 1] = s1;
    }
}

// ---------------------------------------------------------------------------
// k_red: per-batch reduce of (sum, sumsq) partials -> stats[b*2], stats[b*2+1]
// grid = NB, block = 256
// ---------------------------------------------------------------------------
__global__ __launch_bounds__(256) void k_red(const float* __restrict__ part,
                                             float* __restrict__ stats) {
    int b = blockIdx.x;
    int tid = threadIdx.x;
    float s0 = 0.f, s1 = 0.f;
    for (int i = tid; i < NI; i += 256) {
        int bi = b * NI + i;
        s0 += part[bi * 2];
        s1 += part[bi * 2 + 1];
    }
    __shared__ float l0[256], l1[256];
    l0[tid] = s0; l1[tid] = s1;
    __syncthreads();
    for (int s = 128; s; s >>= 1) {
        if (tid < s) { l0[tid] += l0[tid + s]; l1[tid] += l1[tid + s]; }
        __syncthreads();
    }
    if (tid == 0) { stats[b * 2] = l0[0]; stats[b * 2 + 1] = l1[0]; }
}

// ---------------------------------------------------------------------------
// k_Y: Y[b,i,c] = V + (LN1(Va) @ W2^T + b2); emits LN2 partials per (b,i)
// grid = NB*NI, block = 64 (one wave)
// ---------------------------------------------------------------------------
__global__ __launch_bounds__(64) void k_Y(const float* __restrict__ V,
                                          const float* __restrict__ W2,
                                          const float* __restrict__ b2,
                                          const float* __restrict__ Va,
                                          const float* __restrict__ stats1,
                                          float* __restrict__ Y,
                                          float* __restrict__ part2) {
    int bi = blockIdx.x;
    int b = bi >> 9;
    int c = threadIdx.x;
    const float n = (float)(NI * NC);
    float mu = stats1[b * 2] / n;
    float var = stats1[b * 2 + 1] / n - mu * mu;
    float rstd = rsqrtf(var + LN_EPS);

    __shared__ float xn[NC];
    xn[c] = (Va[(size_t)bi * NC + c] - mu) * rstd;
    __syncthreads();

    const float* w = W2 + c * NC;
    float acc = b2[c];
#pragma unroll
    for (int j = 0; j < NC; ++j) acc += xn[j] * w[j];
    float y = V[(size_t)bi * NC + c] + acc;
    Y[(size_t)bi * NC + c] = y;

    float s0 = y, s1 = y * y;
    for (int off = 32; off; off >>= 1) {
        s0 += __shfl_down(s0, off);
        s1 += __shfl_down(s1, off);
    }
    if (c == 0) { part2[bi * 2] = s0; part2[bi * 2 + 1] = s1; }
}

// ---------------------------------------------------------------------------
// k_out: out = LN2(Y), elementwise with per-b stats
// ---------------------------------------------------------------------------
__global__ __launch_bounds__(256) void k_out(const float* __restrict__ Y,
                                             const float* __restrict__ stats2,
                                             float* __restrict__ out) {
    int idx = blockIdx.x * 256 + threadIdx.x;
    int b = idx >> 15;               // / (NI*NC)
    const float n = (float)(NI * NC);
    float mu = stats2[b * 2] / n;
    float var = stats2[b * 2 + 1] / n - mu * mu;
    float rstd = rsqrtf(var + LN_EPS);
    out[idx] = (Y[idx] - mu) * rstd;
}

// ---------------------------------------------------------------------------
extern "C" void kernel_launch(void* const* d_in, const int* in_sizes, int n_in,
                              void* d_out, int out_size, void* d_ws, size_t ws_size,
                              hipStream_t stream) {
    const float* V  = (const float*)d_in[0];
    const float* Q  = (const float*)d_in[1];
    const float* z  = (const float*)d_in[2];
    const float* zm = (const float*)d_in[3];
    const float* W1 = (const float*)d_in[4];
    const float* b1 = (const float*)d_in[5];
    const float* W2 = (const float*)d_in[6];
    const float* b2 = (const float*)d_in[7];
    // d_in[8] is dim == 1 (fixed by setup_inputs)

    float* ws     = (float*)d_ws;
    float* S      = ws;                         // 131072 floats
    float* R      = ws + 131072;                // 131072
    float* Va     = ws + 262144;                // 131072
    float* Y      = ws + 393216;                // 131072
    float* part1  = ws + 524288;                // 4096
    float* part2  = ws + 528384;                // 4096
    float* stats1 = ws + 532480;                // 8
    float* stats2 = ws + 532488;                // 8

    hipMemsetAsync(S, 0, 131072 * sizeof(float), stream);

    // Per-batch phase pipelining: z_b (67 MB) stays resident in the 256 MB
    // Infinity Cache between k_S(b) and k_Va(b), so the second z pass reads
    // from L3 instead of HBM.
    for (int b = 0; b < NB; ++b) {
        k_S <<<512, 256, 0, stream>>>(z, zm, S, b);
        k_R <<<512, 64,  0, stream>>>(Q, W1, b1, S, R, b);
        k_Va<<<512, 256, 0, stream>>>(z, zm, R, Va, part1, b);
    }
    k_red<<<NB, 256, 0, stream>>>(part1, stats1);
    k_Y  <<<NB * NI, 64, 0, stream>>>(V, W2, b2, Va, stats1, Y, part2);
    k_red<<<NB, 256, 0, stream>>>(part2, stats2);
    k_out<<<(NB * NI * NC) / 256, 256, 0, stream>>>(Y, stats2, (float*)d_out);
}

// Round 4
// 435.011 us; speedup vs baseline: 1.1723x; 1.0673x over previous
//
#include <hip/hip_runtime.h>

// Problem constants (fixed by setup_inputs)
constexpr int NB = 4;
constexpr int NI = 512;
constexpr int NK = 512;
constexpr int NC = 64;
constexpr float LN_EPS = 1e-5f;
constexpr int SCHUNK = 8;           // i-chunks in k_S (partial buffers)

// ---------------------------------------------------------------------------
// k_S: S_part[ic][b,k,c] = sum_{i in chunk ic} exp(z[b,i,k,c]) * (mask + 1e-6)
// grid = NB * 32 k-tiles * 8 i-chunks = 1024 blocks, block = 256 (16 k x 16 c4)
// Plain stores to disjoint partial buffers — no atomics, no memset needed.
// ---------------------------------------------------------------------------
__global__ __launch_bounds__(256) void k_S(const float* __restrict__ z,
                                           const float* __restrict__ zmask,
                                           float* __restrict__ S_part) {
    int idx = blockIdx.x;
    int ic = idx & 7;  idx >>= 3;   // i-chunk 0..7 (64 i's each)
    int kt = idx & 31; int b = idx >> 5;
    int tid = threadIdx.x;
    int kk = tid >> 4;              // 0..15
    int c4 = tid & 15;              // 0..15
    int k = kt * 16 + kk;

    float4 acc = make_float4(0.f, 0.f, 0.f, 0.f);
    for (int ii = 0; ii < NI / SCHUNK; ++ii) {
        int i = ic * (NI / SCHUNK) + ii;
        size_t row = ((size_t)(b * NI + i) * NK + k) * NC;
        const float4 zv = *(const float4*)(z + row + c4 * 4);
        float m = zmask[(size_t)(b * NI + i) * NK + k] + 1e-6f;
        acc.x += __expf(zv.x) * m;
        acc.y += __expf(zv.y) * m;
        acc.z += __expf(zv.z) * m;
        acc.w += __expf(zv.w) * m;
    }
    float* sp = S_part + (size_t)ic * (NB * NK * NC)
                       + (size_t)(b * NK + k) * NC + c4 * 4;
    *(float4*)sp = acc;
}

// ---------------------------------------------------------------------------
// k_R: R[b,k,c] = (dot(Q[b,k,:], W1[c,:]) + b1[c]) / sum_ic S_part[ic][b,k,c]
// grid = NB*NK blocks of 64 threads (one per c)
// ---------------------------------------------------------------------------
__global__ __launch_bounds__(64) void k_R(const float* __restrict__ Q,
                                          const float* __restrict__ W1,
                                          const float* __restrict__ b1,
                                          const float* __restrict__ S_part,
                                          float* __restrict__ R) {
    int bk = blockIdx.x;
    int c = threadIdx.x;
    __shared__ float q[NC];
    q[c] = Q[(size_t)bk * NC + c];
    __syncthreads();

    float s = 0.f;
#pragma unroll
    for (int p = 0; p < SCHUNK; ++p)
        s += S_part[(size_t)p * (NB * NK * NC) + (size_t)bk * NC + c];

    const float* w = W1 + c * NC;
    float acc = b1[c];
#pragma unroll
    for (int j = 0; j < NC; ++j) acc += q[j] * w[j];
    R[(size_t)bk * NC + c] = acc / s;
}

// ---------------------------------------------------------------------------
// k_Va: Va[b,i,c] = sum_k mask*(mask+1e-6)*exp(z[b,i,k,c]) * R[b,k,c]
// grid = NB*NI blocks, block = 256 (16 k-stripes x 16 float4-of-c)
// Emits per-(b,i) partial (sum, sumsq) for LN1.
// ---------------------------------------------------------------------------
__global__ __launch_bounds__(256) void k_Va(const float* __restrict__ z,
                                            const float* __restrict__ zmask,
                                            const float* __restrict__ R,
                                            float* __restrict__ Va,
                                            float* __restrict__ part1) {
    int bi = blockIdx.x;
    int b = bi >> 9;                 // / NI
    int tid = threadIdx.x;
    int kk = tid >> 4;
    int c4 = tid & 15;

    const float* zrow = z + (size_t)bi * NK * NC;
    const float* mrow = zmask + (size_t)bi * NK;
    const float* Rb = R + (size_t)b * NK * NC;

    float4 acc = make_float4(0.f, 0.f, 0.f, 0.f);
    for (int kb = 0; kb < NK / 16; ++kb) {
        int k = kb * 16 + kk;
        const float4 zv = *(const float4*)(zrow + (size_t)k * NC + c4 * 4);
        const float4 rv = *(const float4*)(Rb + (size_t)k * NC + c4 * 4);
        float zm = mrow[k];
        float m2 = zm * (zm + 1e-6f);
        acc.x += __expf(zv.x) * m2 * rv.x;
        acc.y += __expf(zv.y) * m2 * rv.y;
        acc.z += __expf(zv.z) * m2 * rv.z;
        acc.w += __expf(zv.w) * m2 * rv.w;
    }

    __shared__ float4 part[256];
    part[tid] = acc;
    __syncthreads();
    // reduce across the 16 kk-stripes (tid = kk*16 + c4)
    for (int s = 128; s >= 16; s >>= 1) {
        if (tid < s) {
            float4 o = part[tid + s];
            float4 m = part[tid];
            m.x += o.x; m.y += o.y; m.z += o.z; m.w += o.w;
            part[tid] = m;
        }
        __syncthreads();
    }
    __shared__ float red[32];
    if (tid < 16) {
        float4 v = part[tid];
        *(float4*)(Va + (size_t)bi * NC + tid * 4) = v;
        red[tid]      = v.x + v.y + v.z + v.w;
        red[16 + tid] = v.x * v.x + v.y * v.y + v.z * v.z + v.w * v.w;
    }
    __syncthreads();
    if (tid == 0) {
        float s0 = 0.f, s1 = 0.f;
        for (int t = 0; t < 16; ++t) { s0 += red[t]; s1 += red[16 + t]; }
        part1[bi * 2]     = s0;
        part1[bi * 2 + 1] = s1;
    }
}

// ---------------------------------------------------------------------------
// k_red: per-batch reduce of (sum, sumsq) partials -> stats[b*2], stats[b*2+1]
// grid = NB, block = 256
// ---------------------------------------------------------------------------
__global__ __launch_bounds__(256) void k_red(const float* __restrict__ part,
                                             float* __restrict__ stats) {
    int b = blockIdx.x;
    int tid = threadIdx.x;
    float s0 = 0.f, s1 = 0.f;
    for (int i = tid; i < NI; i += 256) {
        int bi = b * NI + i;
        s0 += part[bi * 2];
        s1 += part[bi * 2 + 1];
    }
    __shared__ float l0[256], l1[256];
    l0[tid] = s0; l1[tid] = s1;
    __syncthreads();
    for (int s = 128; s; s >>= 1) {
        if (tid < s) { l0[tid] += l0[tid + s]; l1[tid] += l1[tid + s]; }
        __syncthreads();
    }
    if (tid == 0) { stats[b * 2] = l0[0]; stats[b * 2 + 1] = l1[0]; }
}

// ---------------------------------------------------------------------------
// k_Y: Y[b,i,c] = V + (LN1(Va) @ W2^T + b2); emits LN2 partials per (b,i)
// grid = NB*NI, block = 64 (one wave)
// ---------------------------------------------------------------------------
__global__ __launch_bounds__(64) void k_Y(const float* __restrict__ V,
                                          const float* __restrict__ W2,
                                          const float* __restrict__ b2,
                                          const float* __restrict__ Va,
                                          const float* __restrict__ stats1,
                                          float* __restrict__ Y,
                                          float* __restrict__ part2) {
    int bi = blockIdx.x;
    int b = bi >> 9;
    int c = threadIdx.x;
    const float n = (float)(NI * NC);
    float mu = stats1[b * 2] / n;
    float var = stats1[b * 2 + 1] / n - mu * mu;
    float rstd = rsqrtf(var + LN_EPS);

    __shared__ float xn[NC];
    xn[c] = (Va[(size_t)bi * NC + c] - mu) * rstd;
    __syncthreads();

    const float* w = W2 + c * NC;
    float acc = b2[c];
#pragma unroll
    for (int j = 0; j < NC; ++j) acc += xn[j] * w[j];
    float y = V[(size_t)bi * NC + c] + acc;
    Y[(size_t)bi * NC + c] = y;

    float s0 = y, s1 = y * y;
    for (int off = 32; off; off >>= 1) {
        s0 += __shfl_down(s0, off);
        s1 += __shfl_down(s1, off);
    }
    if (c == 0) { part2[bi * 2] = s0; part2[bi * 2 + 1] = s1; }
}

// ---------------------------------------------------------------------------
// k_out: out = LN2(Y), elementwise with per-b stats
// ---------------------------------------------------------------------------
__global__ __launch_bounds__(256) void k_out(const float* __restrict__ Y,
                                             const float* __restrict__ stats2,
                                             float* __restrict__ out) {
    int idx = blockIdx.x * 256 + threadIdx.x;
    int b = idx >> 15;               // / (NI*NC)
    const float n = (float)(NI * NC);
    float mu = stats2[b * 2] / n;
    float var = stats2[b * 2 + 1] / n - mu * mu;
    float rstd = rsqrtf(var + LN_EPS);
    out[idx] = (Y[idx] - mu) * rstd;
}

// ---------------------------------------------------------------------------
extern "C" void kernel_launch(void* const* d_in, const int* in_sizes, int n_in,
                              void* d_out, int out_size, void* d_ws, size_t ws_size,
                              hipStream_t stream) {
    const float* V  = (const float*)d_in[0];
    const float* Q  = (const float*)d_in[1];
    const float* z  = (const float*)d_in[2];
    const float* zm = (const float*)d_in[3];
    const float* W1 = (const float*)d_in[4];
    const float* b1 = (const float*)d_in[5];
    const float* W2 = (const float*)d_in[6];
    const float* b2 = (const float*)d_in[7];
    // d_in[8] is dim == 1 (fixed by setup_inputs)

    float* ws     = (float*)d_ws;
    float* S_part = ws;                          // 8 * 131072 = 1048576 floats
    float* R      = ws + 1048576;                // 131072
    float* Va     = ws + 1179648;                // 131072
    float* Y      = ws + 1310720;                // 131072
    float* part1  = ws + 1441792;                // 4096
    float* part2  = ws + 1445888;                // 4096
    float* stats1 = ws + 1449984;                // 8
    float* stats2 = ws + 1449992;                // 8

    k_S  <<<NB * 32 * SCHUNK, 256, 0, stream>>>(z, zm, S_part);
    k_R  <<<NB * NK,          64,  0, stream>>>(Q, W1, b1, S_part, R);
    k_Va <<<NB * NI,          256, 0, stream>>>(z, zm, R, Va, part1);
    k_red<<<NB,               256, 0, stream>>>(part1, stats1);
    k_Y  <<<NB * NI,          64,  0, stream>>>(V, W2, b2, Va, stats1, Y, part2);
    k_red<<<NB,               256, 0, stream>>>(part2, stats2);
    k_out<<<(NB * NI * NC) / 256, 256, 0, stream>>>(Y, stats2, (float*)d_out);
}